// Round 1
// baseline (1915.856 us; speedup 1.0000x reference)
//
#include <hip/hip_runtime.h>

// LightGCN on MI355X — CSR-build + wave-per-row SpMM, fp32.
// final = (E + A E + A^2 E + A^3 E) / 4,  E = concat(user_emb, item_emb)

#define NU 200000
#define NI 100000
#define NN 300000          // NU + NI
#define DD 64
#define NE 4800000
#define CHUNK 512
#define NCHUNK ((NN + CHUNK - 1) / CHUNK)   // 586

// ---- CSR build ----------------------------------------------------------

__global__ void hist_kernel(const int* __restrict__ rows, int* __restrict__ cnt) {
    int e = blockIdx.x * blockDim.x + threadIdx.x;
    if (e < NE) atomicAdd(&cnt[rows[e]], 1);
}

__global__ void chunk_sum_kernel(const int* __restrict__ cnt, int* __restrict__ csum) {
    int t = blockIdx.x * blockDim.x + threadIdx.x;
    if (t >= NCHUNK) return;
    int r0 = t * CHUNK, r1 = min(NN, r0 + CHUNK);
    int s = 0;
    for (int r = r0; r < r1; ++r) s += cnt[r];
    csum[t] = s;
}

__global__ void scan_kernel(const int* __restrict__ csum, int* __restrict__ coff) {
    __shared__ int sh[1024];
    int t = threadIdx.x;
    int v = (t < NCHUNK) ? csum[t] : 0;
    sh[t] = v;
    __syncthreads();
    for (int o = 1; o < 1024; o <<= 1) {
        int x = (t >= o) ? sh[t - o] : 0;
        __syncthreads();
        sh[t] += x;
        __syncthreads();
    }
    if (t < NCHUNK) coff[t] = sh[t] - v;   // exclusive prefix
}

__global__ void write_off_kernel(const int* __restrict__ cnt, const int* __restrict__ coff,
                                 int* __restrict__ off, int* __restrict__ cursor) {
    int t = blockIdx.x * blockDim.x + threadIdx.x;
    if (t == 0) off[NN] = NE;
    if (t >= NCHUNK) return;
    int run = coff[t];
    int r0 = t * CHUNK, r1 = min(NN, r0 + CHUNK);
    for (int r = r0; r < r1; ++r) {
        off[r] = run;
        cursor[r] = run;
        run += cnt[r];
    }
}

__global__ void scatter_kernel(const int* __restrict__ rows, const int* __restrict__ cols,
                               const float* __restrict__ vals,
                               int* __restrict__ cursor,
                               int* __restrict__ scol, float* __restrict__ sval) {
    int e = blockIdx.x * blockDim.x + threadIdx.x;
    if (e >= NE) return;
    int p = atomicAdd(&cursor[rows[e]], 1);
    scol[p] = cols[e];
    sval[p] = vals[e];
}

// ---- embedding init: cur = acc = concat(user, item) ---------------------

__global__ void init_kernel(const float4* __restrict__ ue, const float4* __restrict__ ie,
                            float4* __restrict__ cur, float4* __restrict__ acc) {
    int i = blockIdx.x * blockDim.x + threadIdx.x;   // over NN*16 float4s
    if (i >= NN * 16) return;
    float4 v = (i < NU * 16) ? ue[i] : ie[i - NU * 16];
    cur[i] = v;
    acc[i] = v;
}

// ---- SpMM: one wave (64 lanes) per row, lane d owns dim d ---------------

__global__ void spmm_kernel(const int* __restrict__ off, const int* __restrict__ scol,
                            const float* __restrict__ sval, const float* __restrict__ cur,
                            float* __restrict__ nxt, float* __restrict__ acc,
                            float scale, int last) {
    int wid  = (blockIdx.x * blockDim.x + threadIdx.x) >> 6;   // row
    int lane = threadIdx.x & 63;
    if (wid >= NN) return;
    int start = off[wid], end = off[wid + 1];
    float sum = 0.f;
    for (int base = start; base < end; base += 64) {
        int n = min(64, end - base);
        int c = 0; float v = 0.f;
        if (lane < n) { c = scol[base + lane]; v = sval[base + lane]; }  // coalesced edge load
        for (int j = 0; j < n; ++j) {
            int   cj = __shfl(c, j);     // broadcast edge col
            float vj = __shfl(v, j);     // broadcast edge val
            sum += vj * cur[cj * DD + lane];   // 256B coalesced gather per edge
        }
    }
    int o = wid * DD + lane;
    if (!last) nxt[o] = sum;
    acc[o] = (acc[o] + sum) * scale;     // fused running sum (+ final /4 on last layer)
}

// ---- launch -------------------------------------------------------------

extern "C" void kernel_launch(void* const* d_in, const int* in_sizes, int n_in,
                              void* d_out, int out_size, void* d_ws, size_t ws_size,
                              hipStream_t stream) {
    const float* ue   = (const float*)d_in[0];
    const float* ie   = (const float*)d_in[1];
    const int*   rows = (const int*)d_in[2];
    const int*   cols = (const int*)d_in[3];
    const float* vals = (const float*)d_in[4];
    float* acc = (float*)d_out;

    char* ws = (char*)d_ws;
    size_t p = 0;
    auto alloc = [&](size_t bytes) -> void* {
        p = (p + 255) & ~(size_t)255;
        void* r = ws + p;
        p += bytes;
        return r;
    };
    float* cur    = (float*)alloc((size_t)NN * DD * 4);   // 76.8 MB
    float* nxt    = (float*)alloc((size_t)NN * DD * 4);   // 76.8 MB
    int*   scol   = (int*)  alloc((size_t)NE * 4);        // 19.2 MB
    float* sval   = (float*)alloc((size_t)NE * 4);        // 19.2 MB
    int*   cnt    = (int*)  alloc((size_t)NN * 4);
    int*   off    = (int*)  alloc((size_t)(NN + 1) * 4);
    int*   cursor = (int*)  alloc((size_t)NN * 4);
    int*   csum   = (int*)  alloc((size_t)NCHUNK * 4);
    int*   coff   = (int*)  alloc((size_t)NCHUNK * 4);

    // 1. CSR build (every call — inputs identical each call, no state carried)
    hipMemsetAsync(cnt, 0, (size_t)NN * 4, stream);
    hist_kernel      <<<(NE + 255) / 256, 256, 0, stream>>>(rows, cnt);
    chunk_sum_kernel <<<(NCHUNK + 255) / 256, 256, 0, stream>>>(cnt, csum);
    scan_kernel      <<<1, 1024, 0, stream>>>(csum, coff);
    write_off_kernel <<<(NCHUNK + 255) / 256, 256, 0, stream>>>(cnt, coff, off, cursor);
    scatter_kernel   <<<(NE + 255) / 256, 256, 0, stream>>>(rows, cols, vals, cursor, scol, sval);

    // 2. cur = acc = E
    init_kernel<<<(NN * 16 + 255) / 256, 256, 0, stream>>>(
        (const float4*)ue, (const float4*)ie, (float4*)cur, (float4*)acc);

    // 3. three propagation layers, acc fused; final scale 1/4 fused into last
    const int spmm_blocks = (NN * 64 + 255) / 256;   // one wave per row
    spmm_kernel<<<spmm_blocks, 256, 0, stream>>>(off, scol, sval, cur, nxt, acc, 1.00f, 0);
    spmm_kernel<<<spmm_blocks, 256, 0, stream>>>(off, scol, sval, nxt, cur, acc, 1.00f, 0);
    spmm_kernel<<<spmm_blocks, 256, 0, stream>>>(off, scol, sval, cur, nxt, acc, 0.25f, 1);
}

// Round 2
// 1469.352 us; speedup vs baseline: 1.3039x; 1.3039x over previous
//
#include <hip/hip_runtime.h>

// LightGCN on MI355X — CSR-build + wave-per-row SpMM, fp32.
// final = (E + A E + A^2 E + A^3 E) / 4,  E = concat(user_emb, item_emb)
//
// R2 changes vs R1:
//  - scatter packs (col,val) into one int2 array: halves random write lines
//  - init_kernel eliminated: spmm layer-1 reads the concat view directly
//    and writes acc = E[row] + sum
//  - spmm inner loop unrolled x8 (batched shuffles -> 8 outstanding gathers)

#define NU 200000
#define NI 100000
#define NN 300000          // NU + NI
#define DD 64
#define NE 4800000
#define CHUNK 512
#define NCHUNK ((NN + CHUNK - 1) / CHUNK)   // 586

// ---- CSR build ----------------------------------------------------------

__global__ void hist_kernel(const int* __restrict__ rows, int* __restrict__ cnt) {
    int e = blockIdx.x * blockDim.x + threadIdx.x;
    if (e < NE) atomicAdd(&cnt[rows[e]], 1);
}

__global__ void chunk_sum_kernel(const int* __restrict__ cnt, int* __restrict__ csum) {
    int t = blockIdx.x * blockDim.x + threadIdx.x;
    if (t >= NCHUNK) return;
    int r0 = t * CHUNK, r1 = min(NN, r0 + CHUNK);
    int s = 0;
    for (int r = r0; r < r1; ++r) s += cnt[r];
    csum[t] = s;
}

__global__ void scan_kernel(const int* __restrict__ csum, int* __restrict__ coff) {
    __shared__ int sh[1024];
    int t = threadIdx.x;
    int v = (t < NCHUNK) ? csum[t] : 0;
    sh[t] = v;
    __syncthreads();
    for (int o = 1; o < 1024; o <<= 1) {
        int x = (t >= o) ? sh[t - o] : 0;
        __syncthreads();
        sh[t] += x;
        __syncthreads();
    }
    if (t < NCHUNK) coff[t] = sh[t] - v;   // exclusive prefix
}

__global__ void write_off_kernel(const int* __restrict__ cnt, const int* __restrict__ coff,
                                 int* __restrict__ off, int* __restrict__ cursor) {
    int t = blockIdx.x * blockDim.x + threadIdx.x;
    if (t == 0) off[NN] = NE;
    if (t >= NCHUNK) return;
    int run = coff[t];
    int r0 = t * CHUNK, r1 = min(NN, r0 + CHUNK);
    for (int r = r0; r < r1; ++r) {
        off[r] = run;
        cursor[r] = run;
        run += cnt[r];
    }
}

__global__ void scatter_kernel(const int* __restrict__ rows, const int* __restrict__ cols,
                               const float* __restrict__ vals,
                               int* __restrict__ cursor,
                               int2* __restrict__ edges) {
    int e = blockIdx.x * blockDim.x + threadIdx.x;
    if (e >= NE) return;
    int p = atomicAdd(&cursor[rows[e]], 1);
    edges[p] = make_int2(cols[e], __float_as_int(vals[e]));   // one 8B random store
}

// ---- SpMM: one wave (64 lanes) per row, lane d owns dim d ---------------
// Gather source is a virtual concat: node c -> (c < NU ? pa : pb2) + c*DD,
// where pb2 is pre-shifted by -NU*DD. For non-first layers pa == pb2 == src.

__global__ void spmm_kernel(const int* __restrict__ off, const int2* __restrict__ edges,
                            const float* __restrict__ pa, const float* __restrict__ pb2,
                            float* __restrict__ nxt, float* __restrict__ acc,
                            int mode) {   // 0 = first layer, 1 = mid, 2 = last
    int wid  = (blockIdx.x * blockDim.x + threadIdx.x) >> 6;   // row
    int lane = threadIdx.x & 63;
    if (wid >= NN) return;
    int start = off[wid], end = off[wid + 1];
    float sum = 0.f;
    for (int base = start; base < end; base += 64) {
        int n = min(64, end - base);
        int c = 0; float v = 0.f;
        if (lane < n) {
            int2 ev = edges[base + lane];          // coalesced 8B/lane
            c = ev.x;
            v = __int_as_float(ev.y);
        }
        int j = 0;
        for (; j + 8 <= n; j += 8) {
            float x[8], vv[8];
            #pragma unroll
            for (int k = 0; k < 8; ++k) {
                int ck = __shfl(c, j + k);                     // broadcast edge col
                vv[k]  = __shfl(v, j + k);                     // broadcast edge val
                const float* p = (ck < NU) ? pa : pb2;
                x[k] = p[(size_t)ck * DD + lane];              // 256B coalesced gather
            }
            #pragma unroll
            for (int k = 0; k < 8; ++k) sum += vv[k] * x[k];
        }
        for (; j < n; ++j) {
            int   cj = __shfl(c, j);
            float vj = __shfl(v, j);
            const float* p = (cj < NU) ? pa : pb2;
            sum += vj * p[(size_t)cj * DD + lane];
        }
    }
    int o = wid * DD + lane;
    if (mode == 0) {
        const float* p = (wid < NU) ? pa : pb2;
        float e0 = p[(size_t)wid * DD + lane];     // E[row] read, replaces init_kernel
        nxt[o] = sum;
        acc[o] = e0 + sum;
    } else if (mode == 1) {
        nxt[o] = sum;
        acc[o] = acc[o] + sum;
    } else {
        acc[o] = (acc[o] + sum) * 0.25f;
    }
}

// ---- launch -------------------------------------------------------------

extern "C" void kernel_launch(void* const* d_in, const int* in_sizes, int n_in,
                              void* d_out, int out_size, void* d_ws, size_t ws_size,
                              hipStream_t stream) {
    const float* ue   = (const float*)d_in[0];
    const float* ie   = (const float*)d_in[1];
    const int*   rows = (const int*)d_in[2];
    const int*   cols = (const int*)d_in[3];
    const float* vals = (const float*)d_in[4];
    float* acc = (float*)d_out;

    char* ws = (char*)d_ws;
    size_t p = 0;
    auto alloc = [&](size_t bytes) -> void* {
        p = (p + 255) & ~(size_t)255;
        void* r = ws + p;
        p += bytes;
        return r;
    };
    float* bufA   = (float*)alloc((size_t)NN * DD * 4);   // 76.8 MB
    float* bufB   = (float*)alloc((size_t)NN * DD * 4);   // 76.8 MB
    int2*  edges  = (int2*) alloc((size_t)NE * 8);        // 38.4 MB packed (col,val)
    int*   cnt    = (int*)  alloc((size_t)NN * 4);
    int*   off    = (int*)  alloc((size_t)(NN + 1) * 4);
    int*   cursor = (int*)  alloc((size_t)NN * 4);
    int*   csum   = (int*)  alloc((size_t)NCHUNK * 4);
    int*   coff   = (int*)  alloc((size_t)NCHUNK * 4);

    // 1. CSR build (every call — harness re-poisons d_ws)
    hipMemsetAsync(cnt, 0, (size_t)NN * 4, stream);
    hist_kernel      <<<(NE + 255) / 256, 256, 0, stream>>>(rows, cnt);
    chunk_sum_kernel <<<(NCHUNK + 255) / 256, 256, 0, stream>>>(cnt, csum);
    scan_kernel      <<<1, 1024, 0, stream>>>(csum, coff);
    write_off_kernel <<<(NCHUNK + 255) / 256, 256, 0, stream>>>(cnt, coff, off, cursor);
    scatter_kernel   <<<(NE + 255) / 256, 256, 0, stream>>>(rows, cols, vals, cursor, edges);

    // 2. three propagation layers; acc (= d_out) fused, final /4 fused into last
    const float* ie2 = ie - (size_t)NU * DD;   // pre-shifted item base for concat view
    const int spmm_blocks = (NN * 64 + 255) / 256;   // one wave per row
    spmm_kernel<<<spmm_blocks, 256, 0, stream>>>(off, edges, ue,   ie2,  bufA, acc, 0);
    spmm_kernel<<<spmm_blocks, 256, 0, stream>>>(off, edges, bufA, bufA, bufB, acc, 1);
    spmm_kernel<<<spmm_blocks, 256, 0, stream>>>(off, edges, bufB, bufB, bufA, acc, 2);
}

// Round 3
// 953.565 us; speedup vs baseline: 2.0092x; 1.5409x over previous
//
#include <hip/hip_runtime.h>

// LightGCN on MI355X — two-phase LDS-staged CSR build + wave-per-row SpMM, fp32.
// final = (E + A E + A^2 E + A^3 E) / 4,  E = concat(user_emb, item_emb)
//
// R3 changes vs R2:
//  - random 8B scatter (298 MB line-amplified writeback) replaced by:
//      bucket_hist -> bucket_scan -> bucket_scatter (LDS-staged, clustered
//      runs) -> fine_sort (per-bucket LDS counting sort, L2-resident)
//  - spmm unchanged from R2 (isolate the sort change)

#define NU 200000
#define NI 100000
#define NN 300000          // NU + NI
#define DD 64
#define NE 4800000
#define NB 2048            // coarse buckets
#define RPB 147            // rows per bucket: 2048*147 = 301056 >= NN
#define CE_HIST 8192       // edges per block, bucket_hist  (586 blocks)
#define CE_SCAT 16384      // edges per block, bucket_scatter (293 blocks)

// ---- Phase 1: bucket histogram (LDS pre-aggregated) ---------------------

__global__ void bucket_hist(const int* __restrict__ rows, int* __restrict__ bcnt) {
    __shared__ int h[NB];
    int tid = threadIdx.x;
    for (int i = tid; i < NB; i += 1024) h[i] = 0;
    __syncthreads();
    int e0 = blockIdx.x * CE_HIST;
    for (int k = 0; k < CE_HIST / 1024; ++k) {
        int e = e0 + k * 1024 + tid;
        if (e < NE) atomicAdd(&h[(unsigned)rows[e] / RPB], 1);
    }
    __syncthreads();
    for (int i = tid; i < NB; i += 1024) {
        int c = h[i];
        if (c) atomicAdd(&bcnt[i], c);
    }
}

// ---- Phase 2a: exclusive scan of 2048 bucket counts ---------------------

__global__ void bucket_scan(const int* __restrict__ bcnt, int* __restrict__ bbase,
                            int* __restrict__ gcursor) {
    __shared__ int sh[1024];
    int t = threadIdx.x;
    int v0 = bcnt[2 * t], v1 = bcnt[2 * t + 1];
    int s = v0 + v1;
    sh[t] = s;
    __syncthreads();
    for (int o = 1; o < 1024; o <<= 1) {
        int x = (t >= o) ? sh[t - o] : 0;
        __syncthreads();
        sh[t] += x;
        __syncthreads();
    }
    int excl = sh[t] - s;                 // exclusive prefix of pair
    bbase[2 * t] = excl;          gcursor[2 * t] = excl;
    bbase[2 * t + 1] = excl + v0; gcursor[2 * t + 1] = excl + v0;
    if (t == 1023) bbase[NB] = sh[1023];  // == NE
}

// ---- Phase 2b: LDS-staged coarse scatter into bucket-grouped records ----
// record: x = (rowlocal << 19) | col   (rowlocal < 147 < 2^13, col < 2^19)
//         y = float bits of val

__global__ void bucket_scatter(const int* __restrict__ rows, const int* __restrict__ cols,
                               const float* __restrict__ vals,
                               int* __restrict__ gcursor, int2* __restrict__ recs) {
    __shared__ int lcnt[NB];
    __shared__ int lbase[NB];
    int tid = threadIdx.x;
    for (int i = tid; i < NB; i += 1024) lcnt[i] = 0;
    __syncthreads();
    int e0 = blockIdx.x * CE_SCAT;
    // pass 1: local histogram
    for (int k = 0; k < CE_SCAT / 1024; ++k) {
        int e = e0 + k * 1024 + tid;
        if (e < NE) atomicAdd(&lcnt[(unsigned)rows[e] / RPB], 1);
    }
    __syncthreads();
    // reserve contiguous runs per bucket, reset local counters to reuse as cursors
    for (int i = tid; i < NB; i += 1024) {
        int c = lcnt[i];
        lbase[i] = c ? atomicAdd(&gcursor[i], c) : 0;
        lcnt[i] = 0;
    }
    __syncthreads();
    // pass 2: place records (runs are contiguous 64B-ish per (block,bucket))
    for (int k = 0; k < CE_SCAT / 1024; ++k) {
        int e = e0 + k * 1024 + tid;
        if (e < NE) {
            int r = rows[e];
            int b = (unsigned)r / RPB;
            int p = lbase[b] + atomicAdd(&lcnt[b], 1);
            int rl = r - b * RPB;
            recs[p] = make_int2((rl << 19) | cols[e], __float_as_int(vals[e]));
        }
    }
}

// ---- Phase 3: per-bucket LDS counting sort -> final CSR -----------------

__global__ void fine_sort(const int* __restrict__ bbase, const int2* __restrict__ recs,
                          int2* __restrict__ edges, int* __restrict__ off) {
    __shared__ int cnt[RPB + 1];
    __shared__ int cur[RPB + 1];
    int b = blockIdx.x, tid = threadIdx.x;
    int e0 = bbase[b], e1 = bbase[b + 1];
    for (int i = tid; i < RPB; i += 256) cnt[i] = 0;
    __syncthreads();
    for (int e = e0 + tid; e < e1; e += 256)
        atomicAdd(&cnt[recs[e].x >> 19], 1);
    __syncthreads();
    if (tid == 0) {
        int run = e0;
        int row0 = b * RPB;
        for (int r = 0; r < RPB; ++r) {
            cur[r] = run;
            int row = row0 + r;
            if (row < NN) off[row] = run;
            run += cnt[r];
        }
    }
    if (b == 0 && tid == 0) off[NN] = NE;
    __syncthreads();
    for (int e = e0 + tid; e < e1; e += 256) {
        int2 rc = recs[e];
        int rl = rc.x >> 19;
        int p = atomicAdd(&cur[rl], 1);
        edges[p] = make_int2(rc.x & 0x7FFFF, rc.y);   // (col, val-bits), L2-resident region
    }
}

// ---- SpMM: one wave (64 lanes) per row, lane d owns dim d ---------------
// Gather source is a virtual concat: node c -> (c < NU ? pa : pb2) + c*DD,
// where pb2 is pre-shifted by -NU*DD. For non-first layers pa == pb2 == src.

__global__ void spmm_kernel(const int* __restrict__ off, const int2* __restrict__ edges,
                            const float* __restrict__ pa, const float* __restrict__ pb2,
                            float* __restrict__ nxt, float* __restrict__ acc,
                            int mode) {   // 0 = first layer, 1 = mid, 2 = last
    int wid  = (blockIdx.x * blockDim.x + threadIdx.x) >> 6;   // row
    int lane = threadIdx.x & 63;
    if (wid >= NN) return;
    int start = off[wid], end = off[wid + 1];
    float sum = 0.f;
    for (int base = start; base < end; base += 64) {
        int n = min(64, end - base);
        int c = 0; float v = 0.f;
        if (lane < n) {
            int2 ev = edges[base + lane];          // coalesced 8B/lane
            c = ev.x;
            v = __int_as_float(ev.y);
        }
        int j = 0;
        for (; j + 8 <= n; j += 8) {
            float x[8], vv[8];
            #pragma unroll
            for (int k = 0; k < 8; ++k) {
                int ck = __shfl(c, j + k);                     // broadcast edge col
                vv[k]  = __shfl(v, j + k);                     // broadcast edge val
                const float* p = (ck < NU) ? pa : pb2;
                x[k] = p[(size_t)ck * DD + lane];              // 256B coalesced gather
            }
            #pragma unroll
            for (int k = 0; k < 8; ++k) sum += vv[k] * x[k];
        }
        for (; j < n; ++j) {
            int   cj = __shfl(c, j);
            float vj = __shfl(v, j);
            const float* p = (cj < NU) ? pa : pb2;
            sum += vj * p[(size_t)cj * DD + lane];
        }
    }
    int o = wid * DD + lane;
    if (mode == 0) {
        const float* p = (wid < NU) ? pa : pb2;
        float e0 = p[(size_t)wid * DD + lane];     // E[row] read, replaces init_kernel
        nxt[o] = sum;
        acc[o] = e0 + sum;
    } else if (mode == 1) {
        nxt[o] = sum;
        acc[o] = acc[o] + sum;
    } else {
        acc[o] = (acc[o] + sum) * 0.25f;
    }
}

// ---- launch -------------------------------------------------------------

extern "C" void kernel_launch(void* const* d_in, const int* in_sizes, int n_in,
                              void* d_out, int out_size, void* d_ws, size_t ws_size,
                              hipStream_t stream) {
    const float* ue   = (const float*)d_in[0];
    const float* ie   = (const float*)d_in[1];
    const int*   rows = (const int*)d_in[2];
    const int*   cols = (const int*)d_in[3];
    const float* vals = (const float*)d_in[4];
    float* acc = (float*)d_out;

    char* ws = (char*)d_ws;
    size_t p = 0;
    auto alloc = [&](size_t bytes) -> void* {
        p = (p + 255) & ~(size_t)255;
        void* r = ws + p;
        p += bytes;
        return r;
    };
    float* bufA    = (float*)alloc((size_t)NN * DD * 4);   // 76.8 MB
    float* bufB    = (float*)alloc((size_t)NN * DD * 4);   // 76.8 MB
    int2*  edges   = (int2*) alloc((size_t)NE * 8);        // 38.4 MB final CSR records
    int*   bcnt    = (int*)  alloc((size_t)NB * 4);
    int*   bbase   = (int*)  alloc((size_t)(NB + 1) * 4);
    int*   gcursor = (int*)  alloc((size_t)NB * 4);
    int*   off     = (int*)  alloc((size_t)(NN + 1) * 4);
    // recs (38.4 MB) aliased onto bufA: dead before spmm first writes bufA
    int2* recs = (int2*)bufA;

    // 1. CSR build: hist -> scan -> coarse bucket scatter -> fine sort
    hipMemsetAsync(bcnt, 0, (size_t)NB * 4, stream);
    bucket_hist   <<<(NE + CE_HIST - 1) / CE_HIST, 1024, 0, stream>>>(rows, bcnt);
    bucket_scan   <<<1, 1024, 0, stream>>>(bcnt, bbase, gcursor);
    bucket_scatter<<<(NE + CE_SCAT - 1) / CE_SCAT, 1024, 0, stream>>>(rows, cols, vals, gcursor, recs);
    fine_sort     <<<NB, 256, 0, stream>>>(bbase, recs, edges, off);

    // 2. three propagation layers; acc (= d_out) fused, final /4 fused into last
    const float* ie2 = ie - (size_t)NU * DD;   // pre-shifted item base for concat view
    const int spmm_blocks = (NN * 64 + 255) / 256;   // one wave per row
    spmm_kernel<<<spmm_blocks, 256, 0, stream>>>(off, edges, ue,   ie2,  bufA, acc, 0);
    spmm_kernel<<<spmm_blocks, 256, 0, stream>>>(off, edges, bufA, bufA, bufB, acc, 1);
    spmm_kernel<<<spmm_blocks, 256, 0, stream>>>(off, edges, bufB, bufB, bufA, acc, 2);
}

// Round 4
// 919.009 us; speedup vs baseline: 2.0847x; 1.0376x over previous
//
#include <hip/hip_runtime.h>

// LightGCN on MI355X — bucket-sort CSR build + 4-row/wave float4 SpMM, fp32.
// final = (E + A E + A^2 E + A^3 E) / 4,  E = concat(user_emb, item_emb)
//
// R4 changes vs R3:
//  - spmm: wave handles 4 rows (16 lanes x float4 each). One inner iter = 4
//    edges: 2 bpermute + 1 dwordx4 gather + 4 fma  (~2.75 inst/edge vs ~10).
//  - spmm templated on layer mode; layers 2/3 drop the concat-view select.
//  - sort pipeline unchanged from R3.

#define NU 200000
#define NI 100000
#define NN 300000          // NU + NI
#define DD 64
#define NE 4800000
#define NB 2048            // coarse buckets
#define RPB 147            // rows per bucket: 2048*147 = 301056 >= NN
#define CE_HIST 8192       // edges per block, bucket_hist  (586 blocks)
#define CE_SCAT 16384      // edges per block, bucket_scatter (293 blocks)

// ---- Phase 1: bucket histogram (LDS pre-aggregated) ---------------------

__global__ void bucket_hist(const int* __restrict__ rows, int* __restrict__ bcnt) {
    __shared__ int h[NB];
    int tid = threadIdx.x;
    for (int i = tid; i < NB; i += 1024) h[i] = 0;
    __syncthreads();
    int e0 = blockIdx.x * CE_HIST;
    for (int k = 0; k < CE_HIST / 1024; ++k) {
        int e = e0 + k * 1024 + tid;
        if (e < NE) atomicAdd(&h[(unsigned)rows[e] / RPB], 1);
    }
    __syncthreads();
    for (int i = tid; i < NB; i += 1024) {
        int c = h[i];
        if (c) atomicAdd(&bcnt[i], c);
    }
}

// ---- Phase 2a: exclusive scan of 2048 bucket counts ---------------------

__global__ void bucket_scan(const int* __restrict__ bcnt, int* __restrict__ bbase,
                            int* __restrict__ gcursor) {
    __shared__ int sh[1024];
    int t = threadIdx.x;
    int v0 = bcnt[2 * t], v1 = bcnt[2 * t + 1];
    int s = v0 + v1;
    sh[t] = s;
    __syncthreads();
    for (int o = 1; o < 1024; o <<= 1) {
        int x = (t >= o) ? sh[t - o] : 0;
        __syncthreads();
        sh[t] += x;
        __syncthreads();
    }
    int excl = sh[t] - s;                 // exclusive prefix of pair
    bbase[2 * t] = excl;          gcursor[2 * t] = excl;
    bbase[2 * t + 1] = excl + v0; gcursor[2 * t + 1] = excl + v0;
    if (t == 1023) bbase[NB] = sh[1023];  // == NE
}

// ---- Phase 2b: LDS-staged coarse scatter into bucket-grouped records ----
// record: x = (rowlocal << 19) | col   (rowlocal < 147 < 2^13, col < 2^19)
//         y = float bits of val

__global__ void bucket_scatter(const int* __restrict__ rows, const int* __restrict__ cols,
                               const float* __restrict__ vals,
                               int* __restrict__ gcursor, int2* __restrict__ recs) {
    __shared__ int lcnt[NB];
    __shared__ int lbase[NB];
    int tid = threadIdx.x;
    for (int i = tid; i < NB; i += 1024) lcnt[i] = 0;
    __syncthreads();
    int e0 = blockIdx.x * CE_SCAT;
    // pass 1: local histogram
    for (int k = 0; k < CE_SCAT / 1024; ++k) {
        int e = e0 + k * 1024 + tid;
        if (e < NE) atomicAdd(&lcnt[(unsigned)rows[e] / RPB], 1);
    }
    __syncthreads();
    // reserve contiguous runs per bucket, reset local counters to reuse as cursors
    for (int i = tid; i < NB; i += 1024) {
        int c = lcnt[i];
        lbase[i] = c ? atomicAdd(&gcursor[i], c) : 0;
        lcnt[i] = 0;
    }
    __syncthreads();
    // pass 2: place records (runs are contiguous per (block,bucket))
    for (int k = 0; k < CE_SCAT / 1024; ++k) {
        int e = e0 + k * 1024 + tid;
        if (e < NE) {
            int r = rows[e];
            int b = (unsigned)r / RPB;
            int p = lbase[b] + atomicAdd(&lcnt[b], 1);
            int rl = r - b * RPB;
            recs[p] = make_int2((rl << 19) | cols[e], __float_as_int(vals[e]));
        }
    }
}

// ---- Phase 3: per-bucket LDS counting sort -> final CSR -----------------

__global__ void fine_sort(const int* __restrict__ bbase, const int2* __restrict__ recs,
                          int2* __restrict__ edges, int* __restrict__ off) {
    __shared__ int cnt[RPB + 1];
    __shared__ int cur[RPB + 1];
    int b = blockIdx.x, tid = threadIdx.x;
    int e0 = bbase[b], e1 = bbase[b + 1];
    for (int i = tid; i < RPB; i += 256) cnt[i] = 0;
    __syncthreads();
    for (int e = e0 + tid; e < e1; e += 256)
        atomicAdd(&cnt[recs[e].x >> 19], 1);
    __syncthreads();
    if (tid == 0) {
        int run = e0;
        int row0 = b * RPB;
        for (int r = 0; r < RPB; ++r) {
            cur[r] = run;
            int row = row0 + r;
            if (row < NN) off[row] = run;
            run += cnt[r];
        }
    }
    if (b == 0 && tid == 0) off[NN] = NE;
    __syncthreads();
    for (int e = e0 + tid; e < e1; e += 256) {
        int2 rc = recs[e];
        int rl = rc.x >> 19;
        int p = atomicAdd(&cur[rl], 1);
        edges[p] = make_int2(rc.x & 0x7FFFF, rc.y);   // (col, val-bits)
    }
}

// ---- SpMM: 4 rows per wave; lane = (g = lane>>4 row, sub = lane&15 dims) --
// One inner iteration processes one edge per 16-lane group (4 edges/wave):
//   2 bpermute broadcasts + 1 global_load_dwordx4 + 4 fma.
// Tail handling is branch-free: lanes beyond the group's edge count hold
// (c,v) = (0,0), so broadcast yields v=0 (fma no-op; gather of row 0 harmless).
// MODE 0: first layer (concat view via pa/pb2, acc = E[row] + sum)
// MODE 1: mid layer    (acc += sum)
// MODE 2: last layer   (acc = (acc + sum) * 0.25)

template <int MODE>
__global__ void spmm4_kernel(const int* __restrict__ off, const int2* __restrict__ edges,
                             const float* __restrict__ pa, const float* __restrict__ pb2,
                             float* __restrict__ nxt, float* __restrict__ acc) {
    int wave = (blockIdx.x * blockDim.x + threadIdx.x) >> 6;
    int lane = threadIdx.x & 63;
    int g    = lane >> 4;         // row within quad
    int sub  = lane & 15;         // dim group (4 floats)
    int row  = wave * 4 + g;
    if (row >= NN) return;        // NN % 4 == 0, so whole waves retire together

    int start = off[row], end = off[row + 1];
    int len = end - start;
    // wave-max chunk count across the 4 groups
    int nchunk = (len + 15) >> 4;
    nchunk = max(nchunk, __shfl_xor(nchunk, 16));
    nchunk = max(nchunk, __shfl_xor(nchunk, 32));

    float4 sum = make_float4(0.f, 0.f, 0.f, 0.f);
    for (int t = 0; t < nchunk; ++t) {
        int myBase = start + t * 16;
        int rem = end - myBase;                 // group-uniform (may be <= 0)
        int c = 0; float v = 0.f;
        if (sub < rem) {
            int2 ev = edges[myBase + sub];      // 128B/segment coalesced
            c = ev.x;
            v = __int_as_float(ev.y);
        }
        // wave-max live count this chunk
        int m = min(rem, 16); m = max(m, 0);
        m = max(m, __shfl_xor(m, 16));
        m = max(m, __shfl_xor(m, 32));
        int gbase = g << 4;
        for (int j = 0; j < m; ++j) {
            int   cj = __shfl(c, gbase + j);    // broadcast edge col within group
            float vj = __shfl(v, gbase + j);    // broadcast edge val
            const float* p = (MODE == 0) ? ((cj < NU) ? pa : pb2) : pa;
            float4 x = ((const float4*)(p + (size_t)cj * DD))[sub];  // 256B/group
            sum.x += vj * x.x; sum.y += vj * x.y;
            sum.z += vj * x.z; sum.w += vj * x.w;
        }
    }

    size_t o4 = (size_t)row * (DD / 4) + sub;   // float4 index; 1KB contiguous/wave
    float4* acc4 = (float4*)acc;
    if (MODE == 0) {
        const float* p = (row < NU) ? pa : pb2;
        float4 e0 = ((const float4*)(p + (size_t)row * DD))[sub];
        ((float4*)nxt)[o4] = sum;
        acc4[o4] = make_float4(e0.x + sum.x, e0.y + sum.y, e0.z + sum.z, e0.w + sum.w);
    } else if (MODE == 1) {
        float4 a = acc4[o4];
        ((float4*)nxt)[o4] = sum;
        acc4[o4] = make_float4(a.x + sum.x, a.y + sum.y, a.z + sum.z, a.w + sum.w);
    } else {
        float4 a = acc4[o4];
        acc4[o4] = make_float4((a.x + sum.x) * 0.25f, (a.y + sum.y) * 0.25f,
                               (a.z + sum.z) * 0.25f, (a.w + sum.w) * 0.25f);
    }
}

// ---- launch -------------------------------------------------------------

extern "C" void kernel_launch(void* const* d_in, const int* in_sizes, int n_in,
                              void* d_out, int out_size, void* d_ws, size_t ws_size,
                              hipStream_t stream) {
    const float* ue   = (const float*)d_in[0];
    const float* ie   = (const float*)d_in[1];
    const int*   rows = (const int*)d_in[2];
    const int*   cols = (const int*)d_in[3];
    const float* vals = (const float*)d_in[4];
    float* acc = (float*)d_out;

    char* ws = (char*)d_ws;
    size_t p = 0;
    auto alloc = [&](size_t bytes) -> void* {
        p = (p + 255) & ~(size_t)255;
        void* r = ws + p;
        p += bytes;
        return r;
    };
    float* bufA    = (float*)alloc((size_t)NN * DD * 4);   // 76.8 MB
    float* bufB    = (float*)alloc((size_t)NN * DD * 4);   // 76.8 MB
    int2*  edges   = (int2*) alloc((size_t)NE * 8);        // 38.4 MB final CSR records
    int*   bcnt    = (int*)  alloc((size_t)NB * 4);
    int*   bbase   = (int*)  alloc((size_t)(NB + 1) * 4);
    int*   gcursor = (int*)  alloc((size_t)NB * 4);
    int*   off     = (int*)  alloc((size_t)(NN + 1) * 4);
    // recs (38.4 MB) aliased onto bufA: dead before spmm first writes bufA
    int2* recs = (int2*)bufA;

    // 1. CSR build: hist -> scan -> coarse bucket scatter -> fine sort
    hipMemsetAsync(bcnt, 0, (size_t)NB * 4, stream);
    bucket_hist   <<<(NE + CE_HIST - 1) / CE_HIST, 1024, 0, stream>>>(rows, bcnt);
    bucket_scan   <<<1, 1024, 0, stream>>>(bcnt, bbase, gcursor);
    bucket_scatter<<<(NE + CE_SCAT - 1) / CE_SCAT, 1024, 0, stream>>>(rows, cols, vals, gcursor, recs);
    fine_sort     <<<NB, 256, 0, stream>>>(bbase, recs, edges, off);

    // 2. three propagation layers; acc (= d_out) fused, final /4 fused into last
    const float* ie2 = ie - (size_t)NU * DD;   // pre-shifted item base for concat view
    const int spmm_blocks = ((NN + 3) / 4 * 64 + 255) / 256;   // 4 rows per wave
    spmm4_kernel<0><<<spmm_blocks, 256, 0, stream>>>(off, edges, ue,   ie2,  bufA, acc);
    spmm4_kernel<1><<<spmm_blocks, 256, 0, stream>>>(off, edges, bufA, bufA, bufB, acc);
    spmm4_kernel<2><<<spmm_blocks, 256, 0, stream>>>(off, edges, bufB, bufB, bufA, acc);
}

// Round 5
// 720.498 us; speedup vs baseline: 2.6591x; 1.2755x over previous
//
#include <hip/hip_runtime.h>
#include <hip/hip_fp16.h>

// LightGCN on MI355X — bucket-sort CSR build + 4-row/wave SpMM, fp16 gathers.
// final = (E + A E + A^2 E + A^3 E) / 4,  E = concat(user_emb, item_emb)
//
// R5 changes vs R4:
//  - gather operand table in fp16 (128B rows): halves the dominant L2-miss
//    gather traffic (spmm was memory-bound: FETCH 639MB @ 52% L2 hit).
//    acc stays fp32; E-identity term read from fp32 inputs (exact).
//  - e_to_h conversion kernel (one pass over E).
//  - fine_sort: serial 147-entry offset loop -> parallel scan.
//  - bucket_hist / bucket_scatter histogram passes: int4 edge loads.

#define NU 200000
#define NI 100000
#define NN 300000          // NU + NI
#define DD 64
#define NE 4800000
#define NB 2048            // coarse buckets
#define RPB 147            // rows per bucket: 2048*147 = 301056 >= NN
#define CE_HIST 8192       // edges per block, bucket_hist  (586 blocks)
#define CE_SCAT 16384      // edges per block, bucket_scatter (293 blocks)

// ---- Phase 1: bucket histogram (LDS pre-aggregated, int4 loads) ---------

__global__ void bucket_hist(const int* __restrict__ rows, int* __restrict__ bcnt) {
    __shared__ int h[NB];
    int tid = threadIdx.x;
    for (int i = tid; i < NB; i += 1024) h[i] = 0;
    __syncthreads();
    const int4* r4 = (const int4*)rows;
    int q0 = blockIdx.x * (CE_HIST / 4);
    for (int k = 0; k < CE_HIST / 4096; ++k) {
        int q = q0 + k * 1024 + tid;
        if (q < NE / 4) {
            int4 r = r4[q];
            atomicAdd(&h[(unsigned)r.x / RPB], 1);
            atomicAdd(&h[(unsigned)r.y / RPB], 1);
            atomicAdd(&h[(unsigned)r.z / RPB], 1);
            atomicAdd(&h[(unsigned)r.w / RPB], 1);
        }
    }
    __syncthreads();
    for (int i = tid; i < NB; i += 1024) {
        int c = h[i];
        if (c) atomicAdd(&bcnt[i], c);
    }
}

// ---- Phase 2a: exclusive scan of 2048 bucket counts ---------------------

__global__ void bucket_scan(const int* __restrict__ bcnt, int* __restrict__ bbase,
                            int* __restrict__ gcursor) {
    __shared__ int sh[1024];
    int t = threadIdx.x;
    int v0 = bcnt[2 * t], v1 = bcnt[2 * t + 1];
    int s = v0 + v1;
    sh[t] = s;
    __syncthreads();
    for (int o = 1; o < 1024; o <<= 1) {
        int x = (t >= o) ? sh[t - o] : 0;
        __syncthreads();
        sh[t] += x;
        __syncthreads();
    }
    int excl = sh[t] - s;                 // exclusive prefix of pair
    bbase[2 * t] = excl;          gcursor[2 * t] = excl;
    bbase[2 * t + 1] = excl + v0; gcursor[2 * t + 1] = excl + v0;
    if (t == 1023) bbase[NB] = sh[1023];  // == NE
}

// ---- Phase 2b: LDS-staged coarse scatter into bucket-grouped records ----
// record: x = (rowlocal << 19) | col   (rowlocal < 147 < 2^13, col < 2^19)
//         y = float bits of val

__global__ void bucket_scatter(const int* __restrict__ rows, const int* __restrict__ cols,
                               const float* __restrict__ vals,
                               int* __restrict__ gcursor, int2* __restrict__ recs) {
    __shared__ int lcnt[NB];
    __shared__ int lbase[NB];
    int tid = threadIdx.x;
    for (int i = tid; i < NB; i += 1024) lcnt[i] = 0;
    __syncthreads();
    // pass 1: local histogram (int4 loads)
    const int4* r4 = (const int4*)rows;
    int q0 = blockIdx.x * (CE_SCAT / 4);
    for (int k = 0; k < CE_SCAT / 4096; ++k) {
        int q = q0 + k * 1024 + tid;
        if (q < NE / 4) {
            int4 r = r4[q];
            atomicAdd(&lcnt[(unsigned)r.x / RPB], 1);
            atomicAdd(&lcnt[(unsigned)r.y / RPB], 1);
            atomicAdd(&lcnt[(unsigned)r.z / RPB], 1);
            atomicAdd(&lcnt[(unsigned)r.w / RPB], 1);
        }
    }
    __syncthreads();
    // reserve contiguous runs per bucket, reset local counters to reuse as cursors
    for (int i = tid; i < NB; i += 1024) {
        int c = lcnt[i];
        lbase[i] = c ? atomicAdd(&gcursor[i], c) : 0;
        lcnt[i] = 0;
    }
    __syncthreads();
    // pass 2: place records (runs are contiguous per (block,bucket))
    int e0 = blockIdx.x * CE_SCAT;
    for (int k = 0; k < CE_SCAT / 1024; ++k) {
        int e = e0 + k * 1024 + tid;
        if (e < NE) {
            int r = rows[e];
            int b = (unsigned)r / RPB;
            int p = lbase[b] + atomicAdd(&lcnt[b], 1);
            int rl = r - b * RPB;
            recs[p] = make_int2((rl << 19) | cols[e], __float_as_int(vals[e]));
        }
    }
}

// ---- Phase 3: per-bucket LDS counting sort -> final CSR -----------------

__global__ void fine_sort(const int* __restrict__ bbase, const int2* __restrict__ recs,
                          int2* __restrict__ edges, int* __restrict__ off) {
    __shared__ int cnt[256];   // RPB=147 padded to 256
    __shared__ int scn[256];
    __shared__ int cur[256];
    int b = blockIdx.x, tid = threadIdx.x;
    int e0 = bbase[b], e1 = bbase[b + 1];
    cnt[tid] = 0;
    __syncthreads();
    for (int e = e0 + tid; e < e1; e += 256)
        atomicAdd(&cnt[recs[e].x >> 19], 1);
    __syncthreads();
    // parallel exclusive scan over 256 entries (Hillis-Steele)
    int v = cnt[tid];
    scn[tid] = v;
    __syncthreads();
    for (int o = 1; o < 256; o <<= 1) {
        int x = (tid >= o) ? scn[tid - o] : 0;
        __syncthreads();
        scn[tid] += x;
        __syncthreads();
    }
    int excl = e0 + scn[tid] - v;
    cur[tid] = excl;
    if (tid < RPB) {
        int row = b * RPB + tid;
        if (row < NN) off[row] = excl;
    }
    if (b == 0 && tid == 0) off[NN] = NE;
    __syncthreads();
    for (int e = e0 + tid; e < e1; e += 256) {
        int2 rc = recs[e];
        int rl = rc.x >> 19;
        int p = atomicAdd(&cur[rl], 1);
        edges[p] = make_int2(rc.x & 0x7FFFF, rc.y);   // (col, val-bits)
    }
}

// ---- E (fp32 concat view) -> h0 (fp16, [NN][64]) ------------------------

__global__ void e_to_h(const float4* __restrict__ ue4, const float4* __restrict__ ie4,
                       uint2* __restrict__ h) {
    int i = blockIdx.x * blockDim.x + threadIdx.x;   // over NN*16 float4-groups
    if (i >= NN * 16) return;
    float4 v = (i < NU * 16) ? ue4[i] : ie4[i - NU * 16];
    __half2 a = __float22half2_rn(make_float2(v.x, v.y));
    __half2 b = __float22half2_rn(make_float2(v.z, v.w));
    h[i] = make_uint2(*(unsigned*)&a, *(unsigned*)&b);
}

// ---- SpMM: 4 rows/wave; lane = (g = lane>>4 row, sub = lane&15 dims) ----
// Gathers fp16 rows (128B): lane sub loads uint2 = 4 halves, fp32 accumulate.
// Tail handling branch-free: lanes beyond the group's count hold (c,v)=(0,0).
// MODE 0: acc = E32[row] + sum (E from fp32 inputs);  1: acc += sum;
// MODE 2: acc = (acc + sum) * 0.25, no nxt write.

template <int MODE>
__global__ void spmm4_kernel(const int* __restrict__ off, const int2* __restrict__ edges,
                             const uint2* __restrict__ h,        // fp16 gather table
                             uint2* __restrict__ nxtH,           // fp16 output
                             float* __restrict__ acc,
                             const float* __restrict__ ue, const float* __restrict__ ie2) {
    int wave = (blockIdx.x * blockDim.x + threadIdx.x) >> 6;
    int lane = threadIdx.x & 63;
    int g    = lane >> 4;         // row within quad
    int sub  = lane & 15;         // dim group (4 elems)
    int row  = wave * 4 + g;
    if (row >= NN) return;        // NN % 4 == 0: whole waves retire together

    int start = off[row], end = off[row + 1];
    int len = end - start;
    int nchunk = (len + 15) >> 4;
    nchunk = max(nchunk, __shfl_xor(nchunk, 16));
    nchunk = max(nchunk, __shfl_xor(nchunk, 32));

    float4 sum = make_float4(0.f, 0.f, 0.f, 0.f);
    for (int t = 0; t < nchunk; ++t) {
        int myBase = start + t * 16;
        int rem = end - myBase;                 // group-uniform (may be <= 0)
        int c = 0; float v = 0.f;
        if (sub < rem) {
            int2 ev = edges[myBase + sub];      // coalesced 8B/lane
            c = ev.x;
            v = __int_as_float(ev.y);
        }
        int m = min(rem, 16); m = max(m, 0);
        m = max(m, __shfl_xor(m, 16));
        m = max(m, __shfl_xor(m, 32));
        int gbase = g << 4;
        for (int j = 0; j < m; ++j) {
            int   cj = __shfl(c, gbase + j);    // broadcast edge col within group
            float vj = __shfl(v, gbase + j);    // broadcast edge val
            uint2 hx = h[(size_t)cj * 16 + sub];          // 128B/group fp16 row
            float2 f0 = __half22float2(*(__half2*)&hx.x);
            float2 f1 = __half22float2(*(__half2*)&hx.y);
            sum.x += vj * f0.x; sum.y += vj * f0.y;
            sum.z += vj * f1.x; sum.w += vj * f1.y;
        }
    }

    size_t o = (size_t)row * 16 + sub;
    float4* acc4 = (float4*)acc;
    if (MODE != 2) {
        __half2 a = __float22half2_rn(make_float2(sum.x, sum.y));
        __half2 bb = __float22half2_rn(make_float2(sum.z, sum.w));
        nxtH[o] = make_uint2(*(unsigned*)&a, *(unsigned*)&bb);
    }
    if (MODE == 0) {
        const float* p = (row < NU) ? ue : ie2;
        float4 e0 = ((const float4*)(p + (size_t)row * DD))[sub];
        acc4[o] = make_float4(e0.x + sum.x, e0.y + sum.y, e0.z + sum.z, e0.w + sum.w);
    } else if (MODE == 1) {
        float4 a = acc4[o];
        acc4[o] = make_float4(a.x + sum.x, a.y + sum.y, a.z + sum.z, a.w + sum.w);
    } else {
        float4 a = acc4[o];
        acc4[o] = make_float4((a.x + sum.x) * 0.25f, (a.y + sum.y) * 0.25f,
                              (a.z + sum.z) * 0.25f, (a.w + sum.w) * 0.25f);
    }
}

// ---- launch -------------------------------------------------------------

extern "C" void kernel_launch(void* const* d_in, const int* in_sizes, int n_in,
                              void* d_out, int out_size, void* d_ws, size_t ws_size,
                              hipStream_t stream) {
    const float* ue   = (const float*)d_in[0];
    const float* ie   = (const float*)d_in[1];
    const int*   rows = (const int*)d_in[2];
    const int*   cols = (const int*)d_in[3];
    const float* vals = (const float*)d_in[4];
    float* acc = (float*)d_out;

    char* ws = (char*)d_ws;
    size_t p = 0;
    auto alloc = [&](size_t bytes) -> void* {
        p = (p + 255) & ~(size_t)255;
        void* r = ws + p;
        p += bytes;
        return r;
    };
    int2*  edges   = (int2*) alloc((size_t)NE * 8);         // 38.4 MB final CSR
    uint2* h0      = (uint2*)alloc((size_t)NN * 16 * 8);    // 38.4 MB fp16 table
    uint2* h1      = (uint2*)alloc((size_t)NN * 16 * 8);    // 38.4 MB fp16 table
    int*   bcnt    = (int*)  alloc((size_t)NB * 4);
    int*   bbase   = (int*)  alloc((size_t)(NB + 1) * 4);
    int*   gcursor = (int*)  alloc((size_t)NB * 4);
    int*   off     = (int*)  alloc((size_t)(NN + 1) * 4);
    // recs (38.4 MB) aliases h1: dead after fine_sort, h1 first written by spmm<0>
    int2*  recs = (int2*)h1;
    // h2 aliases h0: h0 dead after spmm<0> (spmm<1> gathers h1 only)
    uint2* h2 = h0;

    // 1. CSR build: hist -> scan -> coarse bucket scatter -> fine sort
    hipMemsetAsync(bcnt, 0, (size_t)NB * 4, stream);
    bucket_hist   <<<(NE + CE_HIST - 1) / CE_HIST, 1024, 0, stream>>>(rows, bcnt);
    bucket_scan   <<<1, 1024, 0, stream>>>(bcnt, bbase, gcursor);
    bucket_scatter<<<(NE + CE_SCAT - 1) / CE_SCAT, 1024, 0, stream>>>(rows, cols, vals, gcursor, recs);
    fine_sort     <<<NB, 256, 0, stream>>>(bbase, recs, edges, off);

    // 2. E -> fp16 table (after fine_sort: recs aliases h1, not h0 — safe order)
    const float* ie2 = ie - (size_t)NU * DD;   // pre-shifted item base for concat view
    e_to_h<<<(NN * 16 + 255) / 256, 256, 0, stream>>>(
        (const float4*)ue, (const float4*)ie2 + (size_t)NU * 16, h0);

    // 3. three propagation layers; acc (= d_out) fused, final /4 fused into last
    const int spmm_blocks = ((NN + 3) / 4 * 64 + 255) / 256;   // 4 rows per wave
    spmm4_kernel<0><<<spmm_blocks, 256, 0, stream>>>(off, edges, h0, h1, acc, ue, ie2);
    spmm4_kernel<1><<<spmm_blocks, 256, 0, stream>>>(off, edges, h1, h2, acc, ue, ie2);
    spmm4_kernel<2><<<spmm_blocks, 256, 0, stream>>>(off, edges, h2, h1, acc, ue, ie2);
}